// Round 1
// baseline (309.087 us; speedup 1.0000x reference)
//
#include <hip/hip_runtime.h>

typedef __attribute__((ext_vector_type(8))) short short8;
typedef __attribute__((ext_vector_type(4))) float f32x4;

#define DEVI static __device__ __forceinline__

constexpr int NB   = 4;     // batch
constexpr int NH   = 2;     // heads
constexpr int SEQ  = 2048;  // Lq = Lk
constexpr int DM   = 512;   // d_model
constexpr int DKV  = 64;    // d_k = d_v
constexpr int HDIM = 128;   // NH * DKV

DEVI unsigned short f2bf(float f) {
    union { float f; unsigned u; } v; v.f = f;
    unsigned r = v.u + 0x7FFFu + ((v.u >> 16) & 1u);
    return (unsigned short)(r >> 16);
}
DEVI float bf2f(unsigned short s) {
    union { unsigned u; float f; } v; v.u = ((unsigned)s) << 16; return v.f;
}
// async global->LDS, 16B per lane. LDS dest = wave-uniform base + lane*16.
DEVI void async16(const void* g, void* l) {
    __builtin_amdgcn_global_load_lds(
        (const __attribute__((address_space(1))) unsigned int*)g,
        (__attribute__((address_space(3))) unsigned int*)l, 16, 0, 0);
}

// ---------------------------------------------------------------------------
// k_prep: weights f32 -> bf16, transposed so MFMA B-operand rows are K-contig.
// Wq/Wk/Wv [512,128] -> Wt [128][512] (n-major).  Wo [128,512] -> Wot [512][128].
__global__ __launch_bounds__(256) void k_prep(
    const float* __restrict__ Wq, const float* __restrict__ Wk,
    const float* __restrict__ Wv, const float* __restrict__ Wo,
    unsigned short* __restrict__ Wqt, unsigned short* __restrict__ Wkt,
    unsigned short* __restrict__ Wvt, unsigned short* __restrict__ Wot) {
    int id = blockIdx.x * 256 + threadIdx.x;        // 0 .. 262143
    int which = id >> 16;
    int rem = id & 65535;
    if (which < 3) {
        const float* W = which == 0 ? Wq : (which == 1 ? Wk : Wv);
        unsigned short* Wt = which == 0 ? Wqt : (which == 1 ? Wkt : Wvt);
        int n = rem >> 9, k = rem & 511;            // dst [128][512]
        Wt[rem] = f2bf(W[k * HDIM + n]);
    } else {
        int n = rem >> 7, k = rem & 127;            // dst [512][128]
        Wot[rem] = f2bf(Wo[k * DM + n]);
    }
}

// ---------------------------------------------------------------------------
// k_proj: X[8192,512] @ W[512,128] + b  ->  per-head bf16 layouts.
// grid (128, 3): x = 64-row tile, y = which of Q/K/V.
// y==0 -> qs[b][h][q][d] scaled by 1/8; y==1 -> kb[b][h][k][d]; y==2 -> vt[b][h][d][k].
__global__ __launch_bounds__(256) void k_proj(
    const float* __restrict__ Qg, const float* __restrict__ Kg, const float* __restrict__ Vg,
    const unsigned short* __restrict__ Wqt, const unsigned short* __restrict__ Wkt,
    const unsigned short* __restrict__ Wvt,
    const float* __restrict__ bq, const float* __restrict__ bk, const float* __restrict__ bv,
    unsigned short* __restrict__ qs, unsigned short* __restrict__ kb,
    unsigned short* __restrict__ vt) {
    __shared__ unsigned short lA[64 * 64];    // A tile (activations), bf16
    __shared__ unsigned short lB[128 * 64];   // B tile (weights), bf16; reused for V transpose

    const int y = blockIdx.y;
    const float* X = y == 0 ? Qg : (y == 1 ? Kg : Vg);
    const unsigned short* Wt = y == 0 ? Wqt : (y == 1 ? Wkt : Wvt);
    const float* bias = y == 0 ? bq : (y == 1 ? bk : bv);
    const float scal = y == 0 ? 0.125f : 1.0f;   // fold 1/sqrt(dk) into q
    const int row0 = blockIdx.x * 64;
    const int tid = threadIdx.x, lane = tid & 63, wv = tid >> 6;
    const int l16 = lane & 15, lq4 = lane >> 4;
    const int wr = wv >> 1, wc = wv & 1;         // wave grid 2x2 over 64x128 tile

    f32x4 acc[2][4];
    #pragma unroll
    for (int i = 0; i < 2; ++i)
        #pragma unroll
        for (int j = 0; j < 4; ++j) acc[i][j] = f32x4{0.f, 0.f, 0.f, 0.f};

    const int arow = tid >> 2, ac0 = (tid & 3) * 16;  // A staging map

    for (int kc = 0; kc < 8; ++kc) {
        // stage A: 64x64 f32 -> bf16 LDS [m][64]
        {
            const float* src = X + (size_t)(row0 + arow) * DM + kc * 64 + ac0;
            unsigned short* dst = &lA[arow * 64 + ac0];
            #pragma unroll
            for (int i = 0; i < 4; ++i) {
                float4 v = *(const float4*)(src + 4 * i);
                unsigned p0 = (unsigned)f2bf(v.x) | ((unsigned)f2bf(v.y) << 16);
                unsigned p1 = (unsigned)f2bf(v.z) | ((unsigned)f2bf(v.w) << 16);
                *(unsigned*)(dst + 4 * i) = p0;
                *(unsigned*)(dst + 4 * i + 2) = p1;
            }
        }
        // stage B (bf16 weights) async: LDS [n][64]
        #pragma unroll
        for (int c = 0; c < 4; ++c) {
            int chunk = wv * 4 + c;
            int n = chunk * 8 + (lane >> 3);
            int kpart = (lane & 7) * 8;
            const void* g = (const char*)Wt + ((size_t)n * DM + kc * 64 + kpart) * 2;
            void* l = (char*)lB + chunk * 1024 + lane * 16;
            async16(g, l);
        }
        __syncthreads();

        #pragma unroll
        for (int ks = 0; ks < 2; ++ks) {
            short8 a[2], b[4];
            #pragma unroll
            for (int mt = 0; mt < 2; ++mt) {
                int m = wr * 32 + mt * 16 + l16;
                a[mt] = *(const short8*)&lA[m * 64 + ks * 32 + lq4 * 8];
            }
            #pragma unroll
            for (int nt = 0; nt < 4; ++nt) {
                int n = wc * 64 + nt * 16 + l16;
                b[nt] = *(const short8*)&lB[n * 64 + ks * 32 + lq4 * 8];
            }
            #pragma unroll
            for (int mt = 0; mt < 2; ++mt)
                #pragma unroll
                for (int nt = 0; nt < 4; ++nt)
                    acc[mt][nt] = __builtin_amdgcn_mfma_f32_16x16x32_bf16(
                        a[mt], b[nt], acc[mt][nt], 0, 0, 0);
        }
        __syncthreads();
    }

    if (y < 2) {
        unsigned short* dstp = (y == 0) ? qs : kb;
        #pragma unroll
        for (int mt = 0; mt < 2; ++mt)
            #pragma unroll
            for (int nt = 0; nt < 4; ++nt) {
                int col = wc * 64 + nt * 16 + l16;
                float bb = bias[col];
                int h = col >> 6, d = col & 63;
                #pragma unroll
                for (int r = 0; r < 4; ++r) {
                    int row = row0 + wr * 32 + mt * 16 + lq4 * 4 + r;
                    int b = row >> 11, pos = row & 2047;
                    float val = (acc[mt][nt][r] + bb) * scal;
                    dstp[((size_t)(b * NH + h) * SEQ + pos) * DKV + d] = f2bf(val);
                }
            }
    } else {
        // V: bounce through LDS to write vt[b][h][d][kpos] coalesced
        #pragma unroll
        for (int mt = 0; mt < 2; ++mt)
            #pragma unroll
            for (int nt = 0; nt < 4; ++nt) {
                int col = wc * 64 + nt * 16 + l16;
                float bb = bias[col];
                #pragma unroll
                for (int r = 0; r < 4; ++r) {
                    int mrow = wr * 32 + mt * 16 + lq4 * 4 + r;
                    lB[col * 64 + mrow] = f2bf(acc[mt][nt][r] + bb);
                }
            }
        __syncthreads();
        int c = tid >> 1, mp = (tid & 1) * 32;
        int b = row0 >> 11, kpos0 = row0 & 2047;
        int h = c >> 6, d = c & 63;
        unsigned short* dst = vt + ((size_t)(b * NH + h) * DKV + d) * SEQ + kpos0 + mp;
        const unsigned short* srcl = &lB[c * 64 + mp];
        #pragma unroll
        for (int i = 0; i < 4; ++i)
            *(uint4*)(dst + 8 * i) = *(const uint4*)(srcl + 8 * i);
    }
}

// ---------------------------------------------------------------------------
// k_pass1: per (b,h,32-row q-tile), L[q] = log(sum_k exp(masked tanh score)).
// grid 512 = 8 bh * 64 q-tiles.
__global__ __launch_bounds__(256) void k_pass1(
    const unsigned short* __restrict__ qs, const unsigned short* __restrict__ kb,
    const int* __restrict__ maskg, float* __restrict__ Lg) {
    __shared__ unsigned short lK[128 * 64];
    __shared__ int lM[128];
    __shared__ float lsum[32];

    const int bx = blockIdx.x;
    const int qt = bx & 63, bh = bx >> 6;
    const int qbase = qt * 32;
    const int b = bh >> 1;
    const int tid = threadIdx.x, lane = tid & 63, wv = tid >> 6;
    const int l16 = lane & 15, lq4 = lane >> 4;

    if (tid < 32) lsum[tid] = 0.f;

    short8 aq[2][2];
    #pragma unroll
    for (int mt = 0; mt < 2; ++mt)
        #pragma unroll
        for (int ks = 0; ks < 2; ++ks) {
            size_t off = ((size_t)bh * SEQ + qbase + mt * 16 + l16) * DKV + ks * 32 + lq4 * 8;
            aq[mt][ks] = *(const short8*)(qs + off);
        }

    float sums[2][4];
    #pragma unroll
    for (int mt = 0; mt < 2; ++mt)
        #pragma unroll
        for (int r = 0; r < 4; ++r) sums[mt][r] = 0.f;

    const char* kbase_ptr = (const char*)(kb + (size_t)bh * SEQ * DKV);

    for (int kt = 0; kt < 16; ++kt) {
        int kbase = kt * 128;
        #pragma unroll
        for (int c = 0; c < 4; ++c) {
            int chunk = wv * 4 + c;
            const void* g = kbase_ptr + (size_t)kbase * 128 + chunk * 1024 + lane * 16;
            void* l = (char*)lK + chunk * 1024 + lane * 16;
            async16(g, l);
        }
        if (tid < 128) lM[tid] = maskg[b * SEQ + kbase + tid];
        __syncthreads();

        f32x4 acc[2][2];
        #pragma unroll
        for (int mt = 0; mt < 2; ++mt)
            #pragma unroll
            for (int nt = 0; nt < 2; ++nt) acc[mt][nt] = f32x4{0.f, 0.f, 0.f, 0.f};
        #pragma unroll
        for (int ks = 0; ks < 2; ++ks) {
            short8 bfr[2];
            #pragma unroll
            for (int nt = 0; nt < 2; ++nt) {
                int n = wv * 32 + nt * 16 + l16;
                bfr[nt] = *(const short8*)&lK[n * 64 + ks * 32 + lq4 * 8];
            }
            #pragma unroll
            for (int mt = 0; mt < 2; ++mt)
                #pragma unroll
                for (int nt = 0; nt < 2; ++nt)
                    acc[mt][nt] = __builtin_amdgcn_mfma_f32_16x16x32_bf16(
                        aq[mt][ks], bfr[nt], acc[mt][nt], 0, 0, 0);
        }
        #pragma unroll
        for (int nt = 0; nt < 2; ++nt) {
            int col = wv * 32 + nt * 16 + l16;
            int mv = lM[col];
            #pragma unroll
            for (int mt = 0; mt < 2; ++mt)
                #pragma unroll
                for (int r = 0; r < 4; ++r) {
                    float x = acc[mt][nt][r];                      // q.k / 8
                    float e2 = __expf(2.f * x);
                    float s10 = 10.f - 20.f * __builtin_amdgcn_rcpf(1.f + e2);
                    float s = mv ? -10.f : s10;
                    sums[mt][r] += __expf(s);
                }
        }
        __syncthreads();
    }

    #pragma unroll
    for (int mt = 0; mt < 2; ++mt)
        #pragma unroll
        for (int r = 0; r < 4; ++r) {
            float v = sums[mt][r];
            v += __shfl_xor(v, 1); v += __shfl_xor(v, 2);
            v += __shfl_xor(v, 4); v += __shfl_xor(v, 8);
            if (l16 == 0) atomicAdd(&lsum[mt * 16 + lq4 * 4 + r], v);
        }
    __syncthreads();
    if (tid < 32) Lg[(size_t)bh * SEQ + qbase + tid] = __logf(lsum[tid]);
}

// ---------------------------------------------------------------------------
// k_pass2: per (b,h,64-row q-tile, half of k-range):
//   attn = masked tanh score - L  -> global (f32) ; out_half += attn @ v
// grid 512 = 8 bh * 32 q-tiles * 2 k-halves.
__global__ __launch_bounds__(256) void k_pass2(
    const unsigned short* __restrict__ qs, const unsigned short* __restrict__ kb,
    const unsigned short* __restrict__ vt, const int* __restrict__ maskg,
    const float* __restrict__ Lg, float* __restrict__ attnG, float* __restrict__ outh2) {
    __shared__ unsigned short lK[128 * 64];      // k tile  [kpos][d]
    __shared__ unsigned short lV[64 * 128];      // v^T tile [d][kpos]
    __shared__ unsigned short lAttn[64 * 136];   // attn tile [q][kpos], +8 pad
    __shared__ int lM[128];

    const int bx = blockIdx.x;
    const int kh = bx & 1;
    const int rest = bx >> 1;
    const int qt = rest & 31, bh = rest >> 5;
    const int qbase = qt * 64;
    const int b = bh >> 1, h = bh & 1;
    const int tid = threadIdx.x, lane = tid & 63, wv = tid >> 6;
    const int l16 = lane & 15, lq4 = lane >> 4;

    short8 aq[4][2];
    #pragma unroll
    for (int mt = 0; mt < 4; ++mt)
        #pragma unroll
        for (int ks = 0; ks < 2; ++ks) {
            size_t off = ((size_t)bh * SEQ + qbase + mt * 16 + l16) * DKV + ks * 32 + lq4 * 8;
            aq[mt][ks] = *(const short8*)(qs + off);
        }

    float Lr[4][4];
    #pragma unroll
    for (int mt = 0; mt < 4; ++mt)
        #pragma unroll
        for (int r = 0; r < 4; ++r)
            Lr[mt][r] = Lg[(size_t)bh * SEQ + qbase + mt * 16 + lq4 * 4 + r];

    f32x4 o[4];
    #pragma unroll
    for (int mt = 0; mt < 4; ++mt) o[mt] = f32x4{0.f, 0.f, 0.f, 0.f};

    const char* kbase_ptr = (const char*)(kb + (size_t)bh * SEQ * DKV);

    for (int kt = kh * 8; kt < kh * 8 + 8; ++kt) {
        int kbase = kt * 128;
        #pragma unroll
        for (int c = 0; c < 4; ++c) {
            int chunk = wv * 4 + c;
            const void* g = kbase_ptr + (size_t)kbase * 128 + chunk * 1024 + lane * 16;
            void* l = (char*)lK + chunk * 1024 + lane * 16;
            async16(g, l);
        }
        #pragma unroll
        for (int c = 0; c < 4; ++c) {
            int chunk = wv * 4 + c;
            int d = chunk * 4 + (lane >> 4);
            int kk = (lane & 15) * 8;
            const void* g = (const char*)vt + (((size_t)bh * DKV + d) * SEQ + kbase + kk) * 2;
            void* l = (char*)lV + chunk * 1024 + lane * 16;
            async16(g, l);
        }
        if (tid < 128) lM[tid] = maskg[b * SEQ + kbase + tid];
        __syncthreads();

        // scores
        f32x4 s[4][2];
        #pragma unroll
        for (int mt = 0; mt < 4; ++mt)
            #pragma unroll
            for (int nt = 0; nt < 2; ++nt) s[mt][nt] = f32x4{0.f, 0.f, 0.f, 0.f};
        #pragma unroll
        for (int ks = 0; ks < 2; ++ks) {
            short8 bfr[2];
            #pragma unroll
            for (int nt = 0; nt < 2; ++nt) {
                int n = wv * 32 + nt * 16 + l16;
                bfr[nt] = *(const short8*)&lK[n * 64 + ks * 32 + lq4 * 8];
            }
            #pragma unroll
            for (int mt = 0; mt < 4; ++mt)
                #pragma unroll
                for (int nt = 0; nt < 2; ++nt)
                    s[mt][nt] = __builtin_amdgcn_mfma_f32_16x16x32_bf16(
                        aq[mt][ks], bfr[nt], s[mt][nt], 0, 0, 0);
        }
        // attn = masked tanh score - L  -> LDS (bf16), C-layout -> row-major
        #pragma unroll
        for (int nt = 0; nt < 2; ++nt) {
            int col = wv * 32 + nt * 16 + l16;
            int mv = lM[col];
            #pragma unroll
            for (int mt = 0; mt < 4; ++mt)
                #pragma unroll
                for (int r = 0; r < 4; ++r) {
                    float x = s[mt][nt][r];
                    float e2 = __expf(2.f * x);
                    float s10 = 10.f - 20.f * __builtin_amdgcn_rcpf(1.f + e2);
                    float a = (mv ? -10.f : s10) - Lr[mt][r];
                    lAttn[(mt * 16 + lq4 * 4 + r) * 136 + col] = f2bf(a);
                }
        }
        __syncthreads();

        // out += attn @ v   (A from lAttn, B from lV)
        #pragma unroll
        for (int ks = 0; ks < 4; ++ks) {
            short8 bfr = *(const short8*)&lV[(wv * 16 + l16) * 128 + ks * 32 + lq4 * 8];
            #pragma unroll
            for (int mt = 0; mt < 4; ++mt) {
                short8 af = *(const short8*)&lAttn[(mt * 16 + l16) * 136 + ks * 32 + lq4 * 8];
                o[mt] = __builtin_amdgcn_mfma_f32_16x16x32_bf16(af, bfr, o[mt], 0, 0, 0);
            }
        }
        // attn tile -> global f32, fully coalesced from LDS
        {
            int mrow = tid >> 2, c0 = (tid & 3) * 32;
            float* gdst = attnG + ((size_t)bh * SEQ + qbase + mrow) * SEQ + kbase + c0;
            const unsigned short* srcl = &lAttn[mrow * 136 + c0];
            #pragma unroll
            for (int i = 0; i < 4; ++i) {
                short8 hv = *(const short8*)(srcl + 8 * i);
                float4 f0, f1;
                f0.x = bf2f((unsigned short)hv[0]); f0.y = bf2f((unsigned short)hv[1]);
                f0.z = bf2f((unsigned short)hv[2]); f0.w = bf2f((unsigned short)hv[3]);
                f1.x = bf2f((unsigned short)hv[4]); f1.y = bf2f((unsigned short)hv[5]);
                f1.z = bf2f((unsigned short)hv[6]); f1.w = bf2f((unsigned short)hv[7]);
                *(float4*)(gdst + 8 * i) = f0;
                *(float4*)(gdst + 8 * i + 4) = f1;
            }
        }
        __syncthreads();
    }

    // partial out-heads (f32, per k-half)
    float* dst = outh2 + (size_t)kh * (8192 * 128);
    #pragma unroll
    for (int mt = 0; mt < 4; ++mt)
        #pragma unroll
        for (int r = 0; r < 4; ++r) {
            int q = qbase + mt * 16 + lq4 * 4 + r;
            int dcol = wv * 16 + l16;
            dst[((size_t)b * SEQ + q) * HDIM + h * DKV + dcol] = o[mt][r];
        }
}

// ---------------------------------------------------------------------------
// k_comb: outh_bf16 = half0 + half1
__global__ __launch_bounds__(256) void k_comb(const float* __restrict__ outh2,
                                              unsigned short* __restrict__ outh) {
    int i = (blockIdx.x * 256 + threadIdx.x) * 4;
    float4 a = *(const float4*)(outh2 + i);
    float4 c = *(const float4*)(outh2 + 1048576 + i);
    unsigned long long pk =
        (unsigned long long)f2bf(a.x + c.x) |
        ((unsigned long long)f2bf(a.y + c.y) << 16) |
        ((unsigned long long)f2bf(a.z + c.z) << 32) |
        ((unsigned long long)f2bf(a.w + c.w) << 48);
    *(unsigned long long*)(outh + i) = pk;
}

// ---------------------------------------------------------------------------
// k_oproj: out = outh[8192,128] @ Wo[128,512] + bo.  grid (64, 4).
__global__ __launch_bounds__(256) void k_oproj(
    const unsigned short* __restrict__ outh, const unsigned short* __restrict__ Wot,
    const float* __restrict__ bo, float* __restrict__ outG) {
    __shared__ unsigned short lA2[128 * 128];
    __shared__ unsigned short lB2[128 * 128];
    const int row0 = blockIdx.x * 128, col0 = blockIdx.y * 128;
    const int tid = threadIdx.x, lane = tid & 63, wv = tid >> 6;
    const int l16 = lane & 15, lq4 = lane >> 4;
    const int wr = wv >> 1, wc = wv & 1;

    #pragma unroll
    for (int c = 0; c < 8; ++c) {
        int chunk = wv * 8 + c;
        const void* g = (const char*)outh + (size_t)row0 * 256 + chunk * 1024 + lane * 16;
        void* l = (char*)lA2 + chunk * 1024 + lane * 16;
        async16(g, l);
    }
    #pragma unroll
    for (int c = 0; c < 8; ++c) {
        int chunk = wv * 8 + c;
        const void* g = (const char*)Wot + (size_t)col0 * 256 + chunk * 1024 + lane * 16;
        void* l = (char*)lB2 + chunk * 1024 + lane * 16;
        async16(g, l);
    }
    __syncthreads();

    f32x4 acc[4][4];
    #pragma unroll
    for (int mt = 0; mt < 4; ++mt)
        #pragma unroll
        for (int nt = 0; nt < 4; ++nt) acc[mt][nt] = f32x4{0.f, 0.f, 0.f, 0.f};

    #pragma unroll
    for (int ks = 0; ks < 4; ++ks) {
        short8 a[4], bfr[4];
        #pragma unroll
        for (int mt = 0; mt < 4; ++mt)
            a[mt] = *(const short8*)&lA2[(wr * 64 + mt * 16 + l16) * 128 + ks * 32 + lq4 * 8];
        #pragma unroll
        for (int nt = 0; nt < 4; ++nt)
            bfr[nt] = *(const short8*)&lB2[(wc * 64 + nt * 16 + l16) * 128 + ks * 32 + lq4 * 8];
        #pragma unroll
        for (int mt = 0; mt < 4; ++mt)
            #pragma unroll
            for (int nt = 0; nt < 4; ++nt)
                acc[mt][nt] = __builtin_amdgcn_mfma_f32_16x16x32_bf16(
                    a[mt], bfr[nt], acc[mt][nt], 0, 0, 0);
    }

    #pragma unroll
    for (int nt = 0; nt < 4; ++nt) {
        int col = col0 + wc * 64 + nt * 16 + l16;
        float bb = bo[col];
        #pragma unroll
        for (int mt = 0; mt < 4; ++mt)
            #pragma unroll
            for (int r = 0; r < 4; ++r) {
                int row = row0 + wr * 64 + mt * 16 + lq4 * 4 + r;
                outG[(size_t)row * DM + col] = acc[mt][nt][r] + bb;
            }
    }
}

// ---------------------------------------------------------------------------
extern "C" void kernel_launch(void* const* d_in, const int* in_sizes, int n_in,
                              void* d_out, int out_size, void* d_ws, size_t ws_size,
                              hipStream_t stream) {
    (void)in_sizes; (void)n_in; (void)out_size; (void)ws_size;
    const float* Qg = (const float*)d_in[0];
    const float* Kg = (const float*)d_in[1];
    const float* Vg = (const float*)d_in[2];
    const int*   maskg = (const int*)d_in[3];   // bool -> int32 (guess; flip to u8 if wrong)
    const float* Wq = (const float*)d_in[4];
    const float* bq = (const float*)d_in[5];
    const float* Wk = (const float*)d_in[6];
    const float* bk = (const float*)d_in[7];
    const float* Wv = (const float*)d_in[8];
    const float* bv = (const float*)d_in[9];
    const float* Wo = (const float*)d_in[10];
    const float* bo = (const float*)d_in[11];

    char* ws = (char*)d_ws;
    unsigned short* qs   = (unsigned short*)(ws);                    // 4 MB
    unsigned short* kb   = (unsigned short*)(ws + (4  << 20));       // 4 MB
    unsigned short* vt   = (unsigned short*)(ws + (8  << 20));       // 4 MB
    float*          outh2= (float*)(ws + (12 << 20));                // 8 MB (2 halves)
    unsigned short* outh = (unsigned short*)(ws + (20 << 20));       // 2 MB
    float*          Lg   = (float*)(ws + (22 << 20));                // 64 KB
    unsigned short* Wqt  = (unsigned short*)(ws + (22 << 20) + 65536);
    unsigned short* Wkt  = (unsigned short*)((char*)Wqt + 131072);
    unsigned short* Wvt  = (unsigned short*)((char*)Wkt + 131072);
    unsigned short* Wot  = (unsigned short*)((char*)Wvt + 131072);

    float* outG  = (float*)d_out;
    float* attnG = outG + (size_t)NB * SEQ * DM;   // 4,194,304 floats in

    hipLaunchKernelGGL(k_prep, dim3(1024), dim3(256), 0, stream,
                       Wq, Wk, Wv, Wo, Wqt, Wkt, Wvt, Wot);
    hipLaunchKernelGGL(k_proj, dim3(128, 3), dim3(256), 0, stream,
                       Qg, Kg, Vg, Wqt, Wkt, Wvt, bq, bk, bv, qs, kb, vt);
    hipLaunchKernelGGL(k_pass1, dim3(512), dim3(256), 0, stream, qs, kb, maskg, Lg);
    hipLaunchKernelGGL(k_pass2, dim3(512), dim3(256), 0, stream,
                       qs, kb, vt, maskg, Lg, attnG, outh2);
    hipLaunchKernelGGL(k_comb, dim3(1024), dim3(256), 0, stream, outh2, outh);
    hipLaunchKernelGGL(k_oproj, dim3(64, 4), dim3(256), 0, stream, outh, Wot, bo, outG);
}

// Round 2
// 261.668 us; speedup vs baseline: 1.1812x; 1.1812x over previous
//
#include <hip/hip_runtime.h>

typedef __attribute__((ext_vector_type(8))) short short8;
typedef __attribute__((ext_vector_type(4))) short short4v;
typedef __attribute__((ext_vector_type(4))) float f32x4;

#define DEVI static __device__ __forceinline__

constexpr int NB   = 4;     // batch
constexpr int NH   = 2;     // heads
constexpr int SEQ  = 2048;  // Lq = Lk
constexpr int DM   = 512;   // d_model
constexpr int DKV  = 64;    // d_k = d_v
constexpr int HDIM = 128;   // NH * DKV

DEVI unsigned short f2bf(float f) {
    union { float f; unsigned u; } v; v.f = f;
    unsigned r = v.u + 0x7FFFu + ((v.u >> 16) & 1u);
    return (unsigned short)(r >> 16);
}
DEVI float bf2f(unsigned short s) {
    union { unsigned u; float f; } v; v.u = ((unsigned)s) << 16; return v.f;
}
// async global->LDS, 16B per lane. LDS dest = wave-uniform base + lane*16.
DEVI void async16(const void* g, void* l) {
    __builtin_amdgcn_global_load_lds(
        (const __attribute__((address_space(1))) unsigned int*)g,
        (__attribute__((address_space(3))) unsigned int*)l, 16, 0, 0);
}

// ---------------------------------------------------------------------------
// k_prep: weights f32 -> bf16, transposed so MFMA B-operand rows are K-contig.
__global__ __launch_bounds__(256) void k_prep(
    const float* __restrict__ Wq, const float* __restrict__ Wk,
    const float* __restrict__ Wv, const float* __restrict__ Wo,
    unsigned short* __restrict__ Wqt, unsigned short* __restrict__ Wkt,
    unsigned short* __restrict__ Wvt, unsigned short* __restrict__ Wot) {
    int id = blockIdx.x * 256 + threadIdx.x;        // 0 .. 262143
    int which = id >> 16;
    int rem = id & 65535;
    if (which < 3) {
        const float* W = which == 0 ? Wq : (which == 1 ? Wk : Wv);
        unsigned short* Wt = which == 0 ? Wqt : (which == 1 ? Wkt : Wvt);
        int n = rem >> 9, k = rem & 511;            // dst [128][512]
        Wt[rem] = f2bf(W[k * HDIM + n]);
    } else {
        int n = rem >> 7, k = rem & 127;            // dst [512][128]
        Wot[rem] = f2bf(Wo[k * DM + n]);
    }
}

// ---------------------------------------------------------------------------
// k_proj: X[8192,512] @ W[512,128] + b  ->  per-head bf16 layouts.
__global__ __launch_bounds__(256) void k_proj(
    const float* __restrict__ Qg, const float* __restrict__ Kg, const float* __restrict__ Vg,
    const unsigned short* __restrict__ Wqt, const unsigned short* __restrict__ Wkt,
    const unsigned short* __restrict__ Wvt,
    const float* __restrict__ bq, const float* __restrict__ bk, const float* __restrict__ bv,
    unsigned short* __restrict__ qs, unsigned short* __restrict__ kb,
    unsigned short* __restrict__ vt) {
    __shared__ unsigned short lA[64 * 64];
    __shared__ unsigned short lB[128 * 64];

    const int y = blockIdx.y;
    const float* X = y == 0 ? Qg : (y == 1 ? Kg : Vg);
    const unsigned short* Wt = y == 0 ? Wqt : (y == 1 ? Wkt : Wvt);
    const float* bias = y == 0 ? bq : (y == 1 ? bk : bv);
    const float scal = y == 0 ? 0.125f : 1.0f;   // fold 1/sqrt(dk) into q
    const int row0 = blockIdx.x * 64;
    const int tid = threadIdx.x, lane = tid & 63, wv = tid >> 6;
    const int l16 = lane & 15, lq4 = lane >> 4;
    const int wr = wv >> 1, wc = wv & 1;

    f32x4 acc[2][4];
    #pragma unroll
    for (int i = 0; i < 2; ++i)
        #pragma unroll
        for (int j = 0; j < 4; ++j) acc[i][j] = f32x4{0.f, 0.f, 0.f, 0.f};

    const int arow = tid >> 2, ac0 = (tid & 3) * 16;

    for (int kc = 0; kc < 8; ++kc) {
        {
            const float* src = X + (size_t)(row0 + arow) * DM + kc * 64 + ac0;
            unsigned short* dst = &lA[arow * 64 + ac0];
            #pragma unroll
            for (int i = 0; i < 4; ++i) {
                float4 v = *(const float4*)(src + 4 * i);
                unsigned p0 = (unsigned)f2bf(v.x) | ((unsigned)f2bf(v.y) << 16);
                unsigned p1 = (unsigned)f2bf(v.z) | ((unsigned)f2bf(v.w) << 16);
                *(unsigned*)(dst + 4 * i) = p0;
                *(unsigned*)(dst + 4 * i + 2) = p1;
            }
        }
        #pragma unroll
        for (int c = 0; c < 4; ++c) {
            int chunk = wv * 4 + c;
            int n = chunk * 8 + (lane >> 3);
            int kpart = (lane & 7) * 8;
            const void* g = (const char*)Wt + ((size_t)n * DM + kc * 64 + kpart) * 2;
            void* l = (char*)lB + chunk * 1024 + lane * 16;
            async16(g, l);
        }
        __syncthreads();

        #pragma unroll
        for (int ks = 0; ks < 2; ++ks) {
            short8 a[2], b[4];
            #pragma unroll
            for (int mt = 0; mt < 2; ++mt) {
                int m = wr * 32 + mt * 16 + l16;
                a[mt] = *(const short8*)&lA[m * 64 + ks * 32 + lq4 * 8];
            }
            #pragma unroll
            for (int nt = 0; nt < 4; ++nt) {
                int n = wc * 64 + nt * 16 + l16;
                b[nt] = *(const short8*)&lB[n * 64 + ks * 32 + lq4 * 8];
            }
            #pragma unroll
            for (int mt = 0; mt < 2; ++mt)
                #pragma unroll
                for (int nt = 0; nt < 4; ++nt)
                    acc[mt][nt] = __builtin_amdgcn_mfma_f32_16x16x32_bf16(
                        a[mt], b[nt], acc[mt][nt], 0, 0, 0);
        }
        __syncthreads();
    }

    if (y < 2) {
        unsigned short* dstp = (y == 0) ? qs : kb;
        #pragma unroll
        for (int mt = 0; mt < 2; ++mt)
            #pragma unroll
            for (int nt = 0; nt < 4; ++nt) {
                int col = wc * 64 + nt * 16 + l16;
                float bb = bias[col];
                int h = col >> 6, d = col & 63;
                #pragma unroll
                for (int r = 0; r < 4; ++r) {
                    int row = row0 + wr * 32 + mt * 16 + lq4 * 4 + r;
                    int b = row >> 11, pos = row & 2047;
                    float val = (acc[mt][nt][r] + bb) * scal;
                    dstp[((size_t)(b * NH + h) * SEQ + pos) * DKV + d] = f2bf(val);
                }
            }
    } else {
        #pragma unroll
        for (int mt = 0; mt < 2; ++mt)
            #pragma unroll
            for (int nt = 0; nt < 4; ++nt) {
                int col = wc * 64 + nt * 16 + l16;
                float bb = bias[col];
                #pragma unroll
                for (int r = 0; r < 4; ++r) {
                    int mrow = wr * 32 + mt * 16 + lq4 * 4 + r;
                    lB[col * 64 + mrow] = f2bf(acc[mt][nt][r] + bb);
                }
            }
        __syncthreads();
        int c = tid >> 1, mp = (tid & 1) * 32;
        int b = row0 >> 11, kpos0 = row0 & 2047;
        int h = c >> 6, d = c & 63;
        unsigned short* dst = vt + ((size_t)(b * NH + h) * DKV + d) * SEQ + kpos0 + mp;
        const unsigned short* srcl = &lB[c * 64 + mp];
        #pragma unroll
        for (int i = 0; i < 4; ++i)
            *(uint4*)(dst + 8 * i) = *(const uint4*)(srcl + 8 * i);
    }
}

// ---------------------------------------------------------------------------
// k_pass1: per (b,h,64-row q-tile, k-quarter): partial sum_k exp(masked tanh score).
// grid 1024 = 8 bh * 32 q-tiles * 4 k-quarters. No atomics: Lpart[4][8*2048].
__global__ __launch_bounds__(256) void k_pass1(
    const unsigned short* __restrict__ qs, const unsigned short* __restrict__ kb,
    const int* __restrict__ maskg, float* __restrict__ Lpart) {
    __shared__ unsigned short lK[128 * 64];
    __shared__ int lM[128];
    __shared__ float lsumW[4 * 64];

    const int bx = blockIdx.x;
    const int ksp = bx & 3;
    const int qt = (bx >> 2) & 31;
    const int bh = bx >> 7;
    const int qbase = qt * 64;
    const int b = bh >> 1;
    const int tid = threadIdx.x, lane = tid & 63, wv = tid >> 6;
    const int l16 = lane & 15, lq4 = lane >> 4;

    short8 aq[4][2];
    #pragma unroll
    for (int mt = 0; mt < 4; ++mt)
        #pragma unroll
        for (int ks = 0; ks < 2; ++ks) {
            size_t off = ((size_t)bh * SEQ + qbase + mt * 16 + l16) * DKV + ks * 32 + lq4 * 8;
            aq[mt][ks] = *(const short8*)(qs + off);
        }

    float sums[4][4];
    #pragma unroll
    for (int mt = 0; mt < 4; ++mt)
        #pragma unroll
        for (int r = 0; r < 4; ++r) sums[mt][r] = 0.f;

    const char* kbase_ptr = (const char*)(kb + (size_t)bh * SEQ * DKV);

    for (int kt = ksp * 4; kt < ksp * 4 + 4; ++kt) {
        int kbase = kt * 128;
        #pragma unroll
        for (int c = 0; c < 4; ++c) {
            int chunk = wv * 4 + c;
            const void* g = kbase_ptr + (size_t)kbase * 128 + chunk * 1024 + lane * 16;
            void* l = (char*)lK + chunk * 1024 + lane * 16;
            async16(g, l);
        }
        if (tid < 128) lM[tid] = maskg[b * SEQ + kbase + tid];
        __syncthreads();

        f32x4 acc[4][2];
        #pragma unroll
        for (int mt = 0; mt < 4; ++mt)
            #pragma unroll
            for (int nt = 0; nt < 2; ++nt) acc[mt][nt] = f32x4{0.f, 0.f, 0.f, 0.f};
        #pragma unroll
        for (int ks = 0; ks < 2; ++ks) {
            short8 bfr[2];
            #pragma unroll
            for (int nt = 0; nt < 2; ++nt) {
                int n = wv * 32 + nt * 16 + l16;
                bfr[nt] = *(const short8*)&lK[n * 64 + ks * 32 + lq4 * 8];
            }
            #pragma unroll
            for (int mt = 0; mt < 4; ++mt)
                #pragma unroll
                for (int nt = 0; nt < 2; ++nt)
                    acc[mt][nt] = __builtin_amdgcn_mfma_f32_16x16x32_bf16(
                        aq[mt][ks], bfr[nt], acc[mt][nt], 0, 0, 0);
        }
        #pragma unroll
        for (int nt = 0; nt < 2; ++nt) {
            int col = wv * 32 + nt * 16 + l16;
            int mv = lM[col];
            #pragma unroll
            for (int mt = 0; mt < 4; ++mt)
                #pragma unroll
                for (int r = 0; r < 4; ++r) {
                    float x = acc[mt][nt][r];                      // q.k / 8
                    float e2 = __expf(2.f * x);
                    float s10 = 10.f - 20.f * __builtin_amdgcn_rcpf(1.f + e2);
                    float s = mv ? -10.f : s10;
                    sums[mt][r] += __expf(s);
                }
        }
        __syncthreads();
    }

    // reduce across the 16 l16 lanes (cols); write per-wave row sums.
    #pragma unroll
    for (int mt = 0; mt < 4; ++mt)
        #pragma unroll
        for (int r = 0; r < 4; ++r) {
            float v = sums[mt][r];
            v += __shfl_xor(v, 1); v += __shfl_xor(v, 2);
            v += __shfl_xor(v, 4); v += __shfl_xor(v, 8);
            if (l16 == 0) lsumW[wv * 64 + mt * 16 + lq4 * 4 + r] = v;
        }
    __syncthreads();
    if (tid < 64) {
        float v = lsumW[tid] + lsumW[64 + tid] + lsumW[128 + tid] + lsumW[192 + tid];
        Lpart[(size_t)ksp * (8 * SEQ) + (size_t)bh * SEQ + qbase + tid] = v;
    }
}

// ---------------------------------------------------------------------------
// k_pass2: per (b,h,64-row q-tile, k-quarter):
//   attn = masked tanh score - log(sum Lpart) -> global (f32) ; out_part += attn @ v
// grid 1024 = 8 bh * 32 q-tiles * 4 k-quarters.
__global__ __launch_bounds__(256) void k_pass2(
    const unsigned short* __restrict__ qs, const unsigned short* __restrict__ kb,
    const unsigned short* __restrict__ vt, const int* __restrict__ maskg,
    const float* __restrict__ Lpart, float* __restrict__ attnG, float* __restrict__ outh2) {
    __shared__ unsigned short lK[128 * 64];      // k tile  [kpos][d]
    __shared__ unsigned short lV[64 * 128];      // v^T tile [d][kpos]
    __shared__ unsigned short lAttn[64 * 136];   // attn tile [q][kpos], +8 pad
    __shared__ int lM[128];

    const int bx = blockIdx.x;
    const int ksp = bx & 3;
    const int qt = (bx >> 2) & 31;
    const int bh = bx >> 7;
    const int qbase = qt * 64;
    const int b = bh >> 1, h = bh & 1;
    const int tid = threadIdx.x, lane = tid & 63, wv = tid >> 6;
    const int l16 = lane & 15, lq4 = lane >> 4;

    short8 aq[4][2];
    #pragma unroll
    for (int mt = 0; mt < 4; ++mt)
        #pragma unroll
        for (int ks = 0; ks < 2; ++ks) {
            size_t off = ((size_t)bh * SEQ + qbase + mt * 16 + l16) * DKV + ks * 32 + lq4 * 8;
            aq[mt][ks] = *(const short8*)(qs + off);
        }

    float Lr[4][4];
    #pragma unroll
    for (int mt = 0; mt < 4; ++mt)
        #pragma unroll
        for (int r = 0; r < 4; ++r) {
            size_t idx = (size_t)bh * SEQ + qbase + mt * 16 + lq4 * 4 + r;
            float s = Lpart[idx] + Lpart[8 * SEQ + idx] +
                      Lpart[2 * 8 * SEQ + idx] + Lpart[3 * 8 * SEQ + idx];
            Lr[mt][r] = __logf(s);
        }

    f32x4 o[4];
    #pragma unroll
    for (int mt = 0; mt < 4; ++mt) o[mt] = f32x4{0.f, 0.f, 0.f, 0.f};

    const char* kbase_ptr = (const char*)(kb + (size_t)bh * SEQ * DKV);

    for (int kt = ksp * 4; kt < ksp * 4 + 4; ++kt) {
        int kbase = kt * 128;
        #pragma unroll
        for (int c = 0; c < 4; ++c) {
            int chunk = wv * 4 + c;
            const void* g = kbase_ptr + (size_t)kbase * 128 + chunk * 1024 + lane * 16;
            void* l = (char*)lK + chunk * 1024 + lane * 16;
            async16(g, l);
        }
        #pragma unroll
        for (int c = 0; c < 4; ++c) {
            int chunk = wv * 4 + c;
            int d = chunk * 4 + (lane >> 4);
            int kk = (lane & 15) * 8;
            const void* g = (const char*)vt + (((size_t)bh * DKV + d) * SEQ + kbase + kk) * 2;
            void* l = (char*)lV + chunk * 1024 + lane * 16;
            async16(g, l);
        }
        if (tid < 128) lM[tid] = maskg[b * SEQ + kbase + tid];
        __syncthreads();

        // scores
        f32x4 s[4][2];
        #pragma unroll
        for (int mt = 0; mt < 4; ++mt)
            #pragma unroll
            for (int nt = 0; nt < 2; ++nt) s[mt][nt] = f32x4{0.f, 0.f, 0.f, 0.f};
        #pragma unroll
        for (int ks = 0; ks < 2; ++ks) {
            short8 bfr[2];
            #pragma unroll
            for (int nt = 0; nt < 2; ++nt) {
                int n = wv * 32 + nt * 16 + l16;
                bfr[nt] = *(const short8*)&lK[n * 64 + ks * 32 + lq4 * 8];
            }
            #pragma unroll
            for (int mt = 0; mt < 4; ++mt)
                #pragma unroll
                for (int nt = 0; nt < 2; ++nt)
                    s[mt][nt] = __builtin_amdgcn_mfma_f32_16x16x32_bf16(
                        aq[mt][ks], bfr[nt], s[mt][nt], 0, 0, 0);
        }
        // attn = masked tanh score - L  -> LDS (bf16), C-layout -> row-major
        #pragma unroll
        for (int nt = 0; nt < 2; ++nt) {
            int col = wv * 32 + nt * 16 + l16;
            int mv = lM[col];
            #pragma unroll
            for (int mt = 0; mt < 4; ++mt)
                #pragma unroll
                for (int r = 0; r < 4; ++r) {
                    float x = s[mt][nt][r];
                    float e2 = __expf(2.f * x);
                    float s10 = 10.f - 20.f * __builtin_amdgcn_rcpf(1.f + e2);
                    float a = (mv ? -10.f : s10) - Lr[mt][r];
                    lAttn[(mt * 16 + lq4 * 4 + r) * 136 + col] = f2bf(a);
                }
        }
        __syncthreads();

        // out += attn @ v   (A from lAttn, B from lV)
        #pragma unroll
        for (int ks = 0; ks < 4; ++ks) {
            short8 bfr = *(const short8*)&lV[(wv * 16 + l16) * 128 + ks * 32 + lq4 * 8];
            #pragma unroll
            for (int mt = 0; mt < 4; ++mt) {
                short8 af = *(const short8*)&lAttn[(mt * 16 + l16) * 136 + ks * 32 + lq4 * 8];
                o[mt] = __builtin_amdgcn_mfma_f32_16x16x32_bf16(af, bfr, o[mt], 0, 0, 0);
            }
        }
        // attn tile -> global f32, coalesced: per instruction each half-wave
        // writes one fully-contiguous 512B row segment.
        #pragma unroll
        for (int j = 0; j < 8; ++j) {
            int row = j * 8 + (tid >> 5);
            int col = (tid & 31) * 4;
            short4v hv = *(const short4v*)&lAttn[row * 136 + col];
            float4 f;
            f.x = bf2f((unsigned short)hv[0]); f.y = bf2f((unsigned short)hv[1]);
            f.z = bf2f((unsigned short)hv[2]); f.w = bf2f((unsigned short)hv[3]);
            float* gdst = attnG + ((size_t)bh * SEQ + qbase + row) * SEQ + kbase + col;
            *(float4*)gdst = f;
        }
        __syncthreads();
    }

    // partial out-heads (f32, per k-quarter)
    float* dst = outh2 + (size_t)ksp * (8192 * HDIM);
    #pragma unroll
    for (int mt = 0; mt < 4; ++mt)
        #pragma unroll
        for (int r = 0; r < 4; ++r) {
            int q = qbase + mt * 16 + lq4 * 4 + r;
            int dcol = wv * 16 + l16;
            dst[((size_t)b * SEQ + q) * HDIM + h * DKV + dcol] = o[mt][r];
        }
}

// ---------------------------------------------------------------------------
// k_comb: outh_bf16 = sum of 4 k-quarter partials
__global__ __launch_bounds__(256) void k_comb(const float* __restrict__ outh2,
                                              unsigned short* __restrict__ outh) {
    int i = (blockIdx.x * 256 + threadIdx.x) * 4;
    float4 a = *(const float4*)(outh2 + i);
    float4 c = *(const float4*)(outh2 + 1048576 + i);
    float4 d = *(const float4*)(outh2 + 2 * 1048576 + i);
    float4 e = *(const float4*)(outh2 + 3 * 1048576 + i);
    unsigned long long pk =
        (unsigned long long)f2bf(a.x + c.x + d.x + e.x) |
        ((unsigned long long)f2bf(a.y + c.y + d.y + e.y) << 16) |
        ((unsigned long long)f2bf(a.z + c.z + d.z + e.z) << 32) |
        ((unsigned long long)f2bf(a.w + c.w + d.w + e.w) << 48);
    *(unsigned long long*)(outh + i) = pk;
}

// ---------------------------------------------------------------------------
// k_oproj: out = outh[8192,128] @ Wo[128,512] + bo.  grid (64, 4).
__global__ __launch_bounds__(256) void k_oproj(
    const unsigned short* __restrict__ outh, const unsigned short* __restrict__ Wot,
    const float* __restrict__ bo, float* __restrict__ outG) {
    __shared__ unsigned short lA2[128 * 128];
    __shared__ unsigned short lB2[128 * 128];
    const int row0 = blockIdx.x * 128, col0 = blockIdx.y * 128;
    const int tid = threadIdx.x, lane = tid & 63, wv = tid >> 6;
    const int l16 = lane & 15, lq4 = lane >> 4;
    const int wr = wv >> 1, wc = wv & 1;

    #pragma unroll
    for (int c = 0; c < 8; ++c) {
        int chunk = wv * 8 + c;
        const void* g = (const char*)outh + (size_t)row0 * 256 + chunk * 1024 + lane * 16;
        void* l = (char*)lA2 + chunk * 1024 + lane * 16;
        async16(g, l);
    }
    #pragma unroll
    for (int c = 0; c < 8; ++c) {
        int chunk = wv * 8 + c;
        const void* g = (const char*)Wot + (size_t)col0 * 256 + chunk * 1024 + lane * 16;
        void* l = (char*)lB2 + chunk * 1024 + lane * 16;
        async16(g, l);
    }
    __syncthreads();

    f32x4 acc[4][4];
    #pragma unroll
    for (int mt = 0; mt < 4; ++mt)
        #pragma unroll
        for (int nt = 0; nt < 4; ++nt) acc[mt][nt] = f32x4{0.f, 0.f, 0.f, 0.f};

    #pragma unroll
    for (int ks = 0; ks < 4; ++ks) {
        short8 a[4], bfr[4];
        #pragma unroll
        for (int mt = 0; mt < 4; ++mt)
            a[mt] = *(const short8*)&lA2[(wr * 64 + mt * 16 + l16) * 128 + ks * 32 + lq4 * 8];
        #pragma unroll
        for (int nt = 0; nt < 4; ++nt)
            bfr[nt] = *(const short8*)&lB2[(wc * 64 + nt * 16 + l16) * 128 + ks * 32 + lq4 * 8];
        #pragma unroll
        for (int mt = 0; mt < 4; ++mt)
            #pragma unroll
            for (int nt = 0; nt < 4; ++nt)
                acc[mt][nt] = __builtin_amdgcn_mfma_f32_16x16x32_bf16(
                    a[mt], bfr[nt], acc[mt][nt], 0, 0, 0);
    }

    #pragma unroll
    for (int nt = 0; nt < 4; ++nt) {
        int col = col0 + wc * 64 + nt * 16 + l16;
        float bb = bo[col];
        #pragma unroll
        for (int mt = 0; mt < 4; ++mt)
            #pragma unroll
            for (int r = 0; r < 4; ++r) {
                int row = row0 + wr * 64 + mt * 16 + lq4 * 4 + r;
                outG[(size_t)row * DM + col] = acc[mt][nt][r] + bb;
            }
    }
}

// ---------------------------------------------------------------------------
extern "C" void kernel_launch(void* const* d_in, const int* in_sizes, int n_in,
                              void* d_out, int out_size, void* d_ws, size_t ws_size,
                              hipStream_t stream) {
    (void)in_sizes; (void)n_in; (void)out_size; (void)ws_size;
    const float* Qg = (const float*)d_in[0];
    const float* Kg = (const float*)d_in[1];
    const float* Vg = (const float*)d_in[2];
    const int*   maskg = (const int*)d_in[3];
    const float* Wq = (const float*)d_in[4];
    const float* bq = (const float*)d_in[5];
    const float* Wk = (const float*)d_in[6];
    const float* bk = (const float*)d_in[7];
    const float* Wv = (const float*)d_in[8];
    const float* bv = (const float*)d_in[9];
    const float* Wo = (const float*)d_in[10];
    const float* bo = (const float*)d_in[11];

    char* ws = (char*)d_ws;
    unsigned short* qs   = (unsigned short*)(ws);                    // 4 MB
    unsigned short* kb   = (unsigned short*)(ws + (4  << 20));       // 4 MB
    unsigned short* vt   = (unsigned short*)(ws + (8  << 20));       // 4 MB
    float*          outh2= (float*)(ws + (12 << 20));                // 16 MB (4 quarters)
    unsigned short* outh = (unsigned short*)(ws + (28 << 20));       // 2 MB
    float*          Lpart= (float*)(ws + (30 << 20));                // 256 KB
    unsigned short* Wqt  = (unsigned short*)(ws + (30 << 20) + 262144);
    unsigned short* Wkt  = (unsigned short*)((char*)Wqt + 131072);
    unsigned short* Wvt  = (unsigned short*)((char*)Wkt + 131072);
    unsigned short* Wot  = (unsigned short*)((char*)Wvt + 131072);

    float* outG  = (float*)d_out;
    float* attnG = outG + (size_t)NB * SEQ * DM;

    hipLaunchKernelGGL(k_prep, dim3(1024), dim3(256), 0, stream,
                       Wq, Wk, Wv, Wo, Wqt, Wkt, Wvt, Wot);
    hipLaunchKernelGGL(k_proj, dim3(128, 3), dim3(256), 0, stream,
                       Qg, Kg, Vg, Wqt, Wkt, Wvt, bq, bk, bv, qs, kb, vt);
    hipLaunchKernelGGL(k_pass1, dim3(1024), dim3(256), 0, stream, qs, kb, maskg, Lpart);
    hipLaunchKernelGGL(k_pass2, dim3(1024), dim3(256), 0, stream,
                       qs, kb, vt, maskg, Lpart, attnG, outh2);
    hipLaunchKernelGGL(k_comb, dim3(1024), dim3(256), 0, stream, outh2, outh);
    hipLaunchKernelGGL(k_oproj, dim3(64, 4), dim3(256), 0, stream, outh, Wot, bo, outG);
}